// Round 9
// baseline (1035.812 us; speedup 1.0000x reference)
//
#include <hip/hip_runtime.h>
#include <math.h>

// Instant-NGP hash grid encoder, MI355X. Round 9: single-dispatch gather
// with atomic level-major work queue.
//
// Evidence so far: r5 coop => pure gather compute for all 16 levels is
// ~435 us with IDEAL traffic (185 MB); r6 (16 launches) = 552 us gather
// => ~117 us of launch/drain gaps; r7 (2x MLP) and r8 (fewer gather
// instrs) both regressed => gather is L1 lane-request-rate bound, not
// latency- or instruction-count-bound. So: keep the proven 8-load encode,
// recover the launch-gap + x-reread overhead by running ONE persistent
// dispatch (2048 blocks = 8/CU, fully co-resident) that pulls 256-point
// tiles from a global atomic counter enumerated level-major. The global
// grab order enforces level phasing (tile of level l+1 only after all
// level-l tiles grabbed) without grid.sync (r5 lesson: that spin costs
// ~300 us/sync) and without launch boundaries (r6 lesson: ~7 us each).

#define LEVELS 16
#define LOG2_T 19
#define TMASK ((1u << LOG2_T) - 1u)
#define QBLOCKS 2048u        // 8 blocks/CU x 256 CUs, VGPR<=64 so co-resident
#define TILE_PTS 256u        // 1 pt/thread/tile; 4096 tiles/level at n=2^20

typedef float f32x2 __attribute__((ext_vector_type(2)));
typedef float f32x4 __attribute__((ext_vector_type(4)));

struct ResArgs { float r[LEVELS]; };

// Proven 8-load encode (round-3/6 form; bit-identical results, absmax 1.9e-6).
__device__ __forceinline__ f32x2 encode_one(
    const f32x2* __restrict__ tbl, float rf,
    float x0, float x1, float x2)
{
    const float sx = x0 * rf, sy = x1 * rf, sz = x2 * rf;
    const float px = floorf(sx), py = floorf(sy), pz = floorf(sz);
    const float fx = sx - px, fy = sy - py, fz = sz - pz;
    const unsigned ix = (unsigned)px, iy = (unsigned)py, iz = (unsigned)pz;
    const unsigned hx0 = ix, hx1 = ix + 1u;
    const unsigned hy0 = iy * 2654435761u, hy1 = hy0 + 2654435761u;
    const unsigned hz0 = iz * 805459861u,  hz1 = hz0 + 805459861u;
    const f32x2 c000 = tbl[(hx0 ^ hy0 ^ hz0) & TMASK];
    const f32x2 c100 = tbl[(hx1 ^ hy0 ^ hz0) & TMASK];
    const f32x2 c010 = tbl[(hx0 ^ hy1 ^ hz0) & TMASK];
    const f32x2 c110 = tbl[(hx1 ^ hy1 ^ hz0) & TMASK];
    const f32x2 c001 = tbl[(hx0 ^ hy0 ^ hz1) & TMASK];
    const f32x2 c101 = tbl[(hx1 ^ hy0 ^ hz1) & TMASK];
    const f32x2 c011 = tbl[(hx0 ^ hy1 ^ hz1) & TMASK];
    const f32x2 c111 = tbl[(hx1 ^ hy1 ^ hz1) & TMASK];
    const float wx1 = fx, wx0 = 1.0f - fx;
    const float wy1 = fy, wy0 = 1.0f - fy;
    const float wz1 = fz, wz0 = 1.0f - fz;
    const float w00 = wy0 * wz0, w10 = wy1 * wz0;
    const float w01 = wy0 * wz1, w11 = wy1 * wz1;
    float w, a0, a1;
    w = wx0 * w00; a0 = w * c000.x;          a1 = w * c000.y;
    w = wx1 * w00; a0 = fmaf(w, c100.x, a0); a1 = fmaf(w, c100.y, a1);
    w = wx0 * w10; a0 = fmaf(w, c010.x, a0); a1 = fmaf(w, c010.y, a1);
    w = wx1 * w10; a0 = fmaf(w, c110.x, a0); a1 = fmaf(w, c110.y, a1);
    w = wx0 * w01; a0 = fmaf(w, c001.x, a0); a1 = fmaf(w, c001.y, a1);
    w = wx1 * w01; a0 = fmaf(w, c101.x, a0); a1 = fmaf(w, c101.y, a1);
    w = wx0 * w11; a0 = fmaf(w, c011.x, a0); a1 = fmaf(w, c011.y, a1);
    w = wx1 * w11; a0 = fmaf(w, c111.x, a0); a1 = fmaf(w, c111.y, a1);
    f32x2 o; o.x = a0; o.y = a1;
    return o;
}

// ---- Single-dispatch gather: level-major atomic tile queue --------------
__global__ __launch_bounds__(256, 8) void ngp_gather_queue(
    const float* __restrict__ x,
    const float* __restrict__ table,
    f32x2* __restrict__ out_t,     // [LEVELS][n] scratch
    unsigned* __restrict__ counter,// zeroed by hipMemsetAsync before launch
    ResArgs res,
    unsigned n)                    // host guarantees n % TILE_PTS == 0
{
    const unsigned tpl = n / TILE_PTS;        // tiles per level
    const unsigned total = tpl * LEVELS;
    __shared__ unsigned s_tile;

    for (;;) {
        if (threadIdx.x == 0u) s_tile = atomicAdd(counter, 1u);
        __syncthreads();
        const unsigned t = s_tile;
        __syncthreads();                      // s_tile consumed before reuse
        if (t >= total) break;                // uniform across block

        const unsigned level = t / tpl;       // level-major => global phasing
        const unsigned base  = (t - level * tpl) * TILE_PTS;
        const unsigned p = base + threadIdx.x;

        // nt x loads: don't let the 12 MB x stream evict the table slice.
        const float x0 = __builtin_nontemporal_load(&x[3u*p]);
        const float x1 = __builtin_nontemporal_load(&x[3u*p+1u]);
        const float x2 = __builtin_nontemporal_load(&x[3u*p+2u]);

        const f32x2* __restrict__ tbl =
            (const f32x2*)table + ((size_t)level << LOG2_T);
        f32x2 o = encode_one(tbl, res.r[level], x0, x1, x2);
        // wave-contiguous 512 B per instruction -> nt safe.
        __builtin_nontemporal_store(o, &out_t[(size_t)level * n + p]);
    }
}

// ---- LDS transpose (round-7, UNCHANGED control: ~85 us) -----------------
__global__ __launch_bounds__(256) void ngp_transpose_lds(
    const f32x2* __restrict__ out_t,
    f32x4* __restrict__ out,       // [n*8] f32x4
    unsigned n)                    // host guarantees n % 256 == 0
{
    __shared__ f32x2 lds[128][LEVELS + 1];
    const unsigned t = threadIdx.x;
    const unsigned pbase = blockIdx.x * 256u;

    #pragma unroll
    for (int half = 0; half < 2; ++half) {
        const unsigned p0 = pbase + (unsigned)half * 128u;
        #pragma unroll
        for (int j = 0; j < 8; ++j) {
            const unsigned idx = (unsigned)j * 256u + t;
            const unsigned l  = idx >> 7;
            const unsigned pp = idx & 127u;
            lds[pp][l] = out_t[(size_t)l * n + p0 + pp];
        }
        __syncthreads();
        #pragma unroll
        for (int j = 0; j < 4; ++j) {
            const unsigned g = (unsigned)j * 256u + t;
            const unsigned p = g >> 3, q = g & 7u;
            const f32x2 a = lds[p][2u*q];
            const f32x2 b = lds[p][2u*q + 1u];
            f32x4 v; v.x = a.x; v.y = a.y; v.z = b.x; v.w = b.y;
            __builtin_nontemporal_store(v, &out[(size_t)p0 * 8u + g]);
        }
        __syncthreads();
    }
}

// ---- Per-level launch path (round-6 proven, 638 us): fallback -----------
__global__ __launch_bounds__(256) void ngp_gather_level(
    const float* __restrict__ x,
    const float* __restrict__ table,
    f32x2* __restrict__ out_t,
    float rf, int level, unsigned n)
{
    const unsigned p = blockIdx.x * 256u + threadIdx.x;
    if (p >= n) return;
    const float x0 = __builtin_nontemporal_load(&x[3u*p]);
    const float x1 = __builtin_nontemporal_load(&x[3u*p+1u]);
    const float x2 = __builtin_nontemporal_load(&x[3u*p+2u]);
    const f32x2* __restrict__ tbl =
        (const f32x2*)table + ((size_t)level << LOG2_T);
    f32x2 o = encode_one(tbl, rf, x0, x1, x2);
    __builtin_nontemporal_store(o, &out_t[(size_t)level * n + p]);
}

// ---- Last-resort direct kernel (round-3 proven) -------------------------
__global__ __launch_bounds__(256) void ngp_encode_direct(
    const float* __restrict__ x,
    const float* __restrict__ table,
    f32x2* __restrict__ out,
    ResArgs res,
    unsigned n_points)
{
    const unsigned t = blockIdx.x * 256u + threadIdx.x;
    const unsigned level = t & (LEVELS - 1u);
    const unsigned p = t >> 4;
    if (p >= n_points) return;
    const float x0 = x[3u*p], x1 = x[3u*p+1u], x2 = x[3u*p+2u];
    const f32x2* __restrict__ tbl =
        (const f32x2*)table + ((size_t)level << LOG2_T);
    f32x2 o = encode_one(tbl, res.r[level], x0, x1, x2);
    __builtin_nontemporal_store(o, &out[t]);
}

extern "C" void kernel_launch(void* const* d_in, const int* in_sizes, int n_in,
                              void* d_out, int out_size, void* d_ws, size_t ws_size,
                              hipStream_t stream) {
    const float* x     = (const float*)d_in[0];
    const float* table = (const float*)d_in[1];
    const unsigned n_points = (unsigned)(in_sizes[0] / 3);

    // numpy RES replication (same host libm).
    ResArgs res;
    const double scale = exp((log(512.0) - log(16.0)) / 15.0);
    for (int l = 0; l < LEVELS; ++l) {
        res.r[l] = (float)floor(16.0 * pow(scale, (double)l));
    }

    const size_t scratch_needed = (size_t)LEVELS * n_points * sizeof(f32x2);
    const bool scratch_ok = (ws_size >= scratch_needed) &&
                            (n_points % 256u == 0u);
    const bool queue_ok = scratch_ok &&
                          (ws_size >= scratch_needed + sizeof(unsigned));

    if (queue_ok) {
        f32x2* out_t = (f32x2*)d_ws;
        unsigned* counter = (unsigned*)((char*)d_ws + scratch_needed);
        hipMemsetAsync(counter, 0, sizeof(unsigned), stream);
        ngp_gather_queue<<<dim3(QBLOCKS), dim3(256), 0, stream>>>(
            x, table, out_t, counter, res, n_points);
        ngp_transpose_lds<<<dim3(n_points / 256u), dim3(256), 0, stream>>>(
            out_t, (f32x4*)d_out, n_points);
    } else if (scratch_ok) {
        f32x2* out_t = (f32x2*)d_ws;
        const unsigned nblk = n_points / 256u;
        for (int l = 0; l < LEVELS; ++l) {
            ngp_gather_level<<<dim3(nblk), dim3(256), 0, stream>>>(
                x, table, out_t, res.r[l], l, n_points);
        }
        ngp_transpose_lds<<<dim3(nblk), dim3(256), 0, stream>>>(
            out_t, (f32x4*)d_out, n_points);
    } else {
        const unsigned total = n_points * LEVELS;
        const unsigned nblk = (total + 255u) / 256u;
        ngp_encode_direct<<<dim3(nblk), dim3(256), 0, stream>>>(
            x, table, (f32x2*)d_out, res, n_points);
    }
}

// Round 10
// 861.266 us; speedup vs baseline: 1.2027x; 1.2027x over previous
//
#include <hip/hip_runtime.h>
#include <math.h>

// Instant-NGP hash grid encoder, MI355X. Round 10: XCD-space level phasing.
//
// History: r5 coop => ideal traffic (185 MB) & pure gather ~435 us, but
// grid.sync spin ruins it. r6 (16 per-level launches) = 638 us best; ~117 us
// lost to launch gaps + 16x x re-read. r9 atomic queue: drift + per-tile
// vmcnt(0) drain => 816 us, FETCH 772 MB. Lesson: queues order grabs, not
// execution. This round phases by SPACE: blockIdx%8 -> XCD (m09/m157);
// XCD k's 256 blocks sweep a weighted contiguous segment of the level-major
// tile axis deterministically (tile = S[k]+q+256j, no atomics/barriers).
// Each XCD L2 holds its OWN current level slice; 8 slices run concurrently.
// 2 dispatches total instead of 17.

#define LEVELS 16
#define LOG2_T 19
#define TMASK ((1u << LOG2_T) - 1u)

typedef float f32x2 __attribute__((ext_vector_type(2)));
typedef float f32x4 __attribute__((ext_vector_type(4)));

struct ResArgs { float r[LEVELS]; };
struct SegArgs { unsigned s[9]; };   // XCD tile-segment boundaries

// Proven 8-load encode (bit-identical results across r3/r6, absmax 1.9e-6).
__device__ __forceinline__ f32x2 encode_one(
    const f32x2* __restrict__ tbl, float rf,
    float x0, float x1, float x2)
{
    const float sx = x0 * rf, sy = x1 * rf, sz = x2 * rf;
    const float px = floorf(sx), py = floorf(sy), pz = floorf(sz);
    const float fx = sx - px, fy = sy - py, fz = sz - pz;
    const unsigned ix = (unsigned)px, iy = (unsigned)py, iz = (unsigned)pz;
    const unsigned hx0 = ix, hx1 = ix + 1u;
    const unsigned hy0 = iy * 2654435761u, hy1 = hy0 + 2654435761u;
    const unsigned hz0 = iz * 805459861u,  hz1 = hz0 + 805459861u;
    const f32x2 c000 = tbl[(hx0 ^ hy0 ^ hz0) & TMASK];
    const f32x2 c100 = tbl[(hx1 ^ hy0 ^ hz0) & TMASK];
    const f32x2 c010 = tbl[(hx0 ^ hy1 ^ hz0) & TMASK];
    const f32x2 c110 = tbl[(hx1 ^ hy1 ^ hz0) & TMASK];
    const f32x2 c001 = tbl[(hx0 ^ hy0 ^ hz1) & TMASK];
    const f32x2 c101 = tbl[(hx1 ^ hy0 ^ hz1) & TMASK];
    const f32x2 c011 = tbl[(hx0 ^ hy1 ^ hz1) & TMASK];
    const f32x2 c111 = tbl[(hx1 ^ hy1 ^ hz1) & TMASK];
    const float wx1 = fx, wx0 = 1.0f - fx;
    const float wy1 = fy, wy0 = 1.0f - fy;
    const float wz1 = fz, wz0 = 1.0f - fz;
    const float w00 = wy0 * wz0, w10 = wy1 * wz0;
    const float w01 = wy0 * wz1, w11 = wy1 * wz1;
    float w, a0, a1;
    w = wx0 * w00; a0 = w * c000.x;          a1 = w * c000.y;
    w = wx1 * w00; a0 = fmaf(w, c100.x, a0); a1 = fmaf(w, c100.y, a1);
    w = wx0 * w10; a0 = fmaf(w, c010.x, a0); a1 = fmaf(w, c010.y, a1);
    w = wx1 * w10; a0 = fmaf(w, c110.x, a0); a1 = fmaf(w, c110.y, a1);
    w = wx0 * w01; a0 = fmaf(w, c001.x, a0); a1 = fmaf(w, c001.y, a1);
    w = wx1 * w01; a0 = fmaf(w, c101.x, a0); a1 = fmaf(w, c101.y, a1);
    w = wx0 * w11; a0 = fmaf(w, c011.x, a0); a1 = fmaf(w, c011.y, a1);
    w = wx1 * w11; a0 = fmaf(w, c111.x, a0); a1 = fmaf(w, c111.y, a1);
    f32x2 o; o.x = a0; o.y = a1;
    return o;
}

// ---- XCD-partitioned gather: one dispatch, deterministic tile sweep -----
__global__ __launch_bounds__(256, 8) void ngp_gather_xcd(
    const float* __restrict__ x,
    const float* __restrict__ table,
    f32x2* __restrict__ out_t,     // [LEVELS][n] scratch
    ResArgs res, SegArgs seg,
    unsigned n)                    // host guarantees n % 256 == 0
{
    const unsigned bid = blockIdx.x;
    const unsigned xcd = bid & 7u;         // HW round-robin XCD mapping
    const unsigned q   = bid >> 3;         // 0..255 within this XCD
    const unsigned tpl = n >> 8;           // tiles per level
    const unsigned tend = seg.s[xcd + 1];

    // Deterministic level-major sweep of this XCD's segment: blocks stay
    // within a ~256-tile moving window -> one 4 MB slice per XCD L2.
    for (unsigned t = seg.s[xcd] + q; t < tend; t += 256u) {
        const unsigned level = t / tpl;         // block-uniform scalar math
        const unsigned idx   = t - level * tpl;
        const unsigned p = idx * 256u + threadIdx.x;

        // nt x loads: 12 B/pt stream must not evict the table slice.
        const float x0 = __builtin_nontemporal_load(&x[3u*p]);
        const float x1 = __builtin_nontemporal_load(&x[3u*p+1u]);
        const float x2 = __builtin_nontemporal_load(&x[3u*p+2u]);

        const f32x2* __restrict__ tbl =
            (const f32x2*)table + ((size_t)level << LOG2_T);
        f32x2 o = encode_one(tbl, res.r[level], x0, x1, x2);
        // wave-contiguous 512 B per instruction -> nt safe (L3 absorbs).
        __builtin_nontemporal_store(o, &out_t[(size_t)level * n + p]);
    }
}

// ---- LDS transpose [L][N] -> [N][L]. One change vs r7 control: final
// stores TEMPORAL so Infinity Cache absorbs the write burst (r7 evidence:
// nt out_t stores were L3-absorbed; transpose looked write-path capped). --
__global__ __launch_bounds__(256) void ngp_transpose_lds(
    const f32x2* __restrict__ out_t,
    f32x4* __restrict__ out,       // [n*8] f32x4
    unsigned n)                    // host guarantees n % 256 == 0
{
    __shared__ f32x2 lds[128][LEVELS + 1];
    const unsigned t = threadIdx.x;
    const unsigned pbase = blockIdx.x * 256u;

    #pragma unroll
    for (int half = 0; half < 2; ++half) {
        const unsigned p0 = pbase + (unsigned)half * 128u;
        #pragma unroll
        for (int j = 0; j < 8; ++j) {
            const unsigned idx = (unsigned)j * 256u + t;
            const unsigned l  = idx >> 7;
            const unsigned pp = idx & 127u;
            lds[pp][l] = out_t[(size_t)l * n + p0 + pp];
        }
        __syncthreads();
        #pragma unroll
        for (int j = 0; j < 4; ++j) {
            const unsigned g = (unsigned)j * 256u + t;
            const unsigned p = g >> 3, q = g & 7u;
            const f32x2 a = lds[p][2u*q];
            const f32x2 b = lds[p][2u*q + 1u];
            f32x4 v; v.x = a.x; v.y = a.y; v.z = b.x; v.w = b.y;
            out[(size_t)p0 * 8u + g] = v;     // temporal: L3 absorbs burst
        }
        __syncthreads();
    }
}

// ---- Fallback (round-3 proven): direct point-major ----------------------
__global__ __launch_bounds__(256) void ngp_encode_direct(
    const float* __restrict__ x,
    const float* __restrict__ table,
    f32x2* __restrict__ out,
    ResArgs res,
    unsigned n_points)
{
    const unsigned t = blockIdx.x * 256u + threadIdx.x;
    const unsigned level = t & (LEVELS - 1u);
    const unsigned p = t >> 4;
    if (p >= n_points) return;
    const float x0 = x[3u*p], x1 = x[3u*p+1u], x2 = x[3u*p+2u];
    const f32x2* __restrict__ tbl =
        (const f32x2*)table + ((size_t)level << LOG2_T);
    f32x2 o = encode_one(tbl, res.r[level], x0, x1, x2);
    __builtin_nontemporal_store(o, &out[t]);
}

extern "C" void kernel_launch(void* const* d_in, const int* in_sizes, int n_in,
                              void* d_out, int out_size, void* d_ws, size_t ws_size,
                              hipStream_t stream) {
    const float* x     = (const float*)d_in[0];
    const float* table = (const float*)d_in[1];
    const unsigned n_points = (unsigned)(in_sizes[0] / 3);

    // numpy RES replication (same host libm).
    ResArgs res;
    const double scale = exp((log(512.0) - log(16.0)) / 15.0);
    for (int l = 0; l < LEVELS; ++l) {
        res.r[l] = (float)floor(16.0 * pow(scale, (double)l));
    }

    const size_t scratch_needed = (size_t)LEVELS * n_points * sizeof(f32x2);
    const bool fits = (ws_size >= scratch_needed) && (n_points % 256u == 0u);

    if (fits) {
        f32x2* out_t = (f32x2*)d_ws;
        const unsigned tpl = n_points >> 8;          // tiles per level

        // Time-weight per level (relative cost; footprint-in-lines model:
        // 0-2 cheap/L2-hot, 3-6 ramp to full slice, 7-15 full 4 MB random).
        static const double wl[LEVELS] =
            {10,10,11,14,19,24,28,30,30,30,30,30,30,30,30,30};
        double cum[LEVELS + 1]; cum[0] = 0.0;
        for (int l = 0; l < LEVELS; ++l) cum[l+1] = cum[l] + wl[l];
        const double tot = cum[LEVELS];

        SegArgs seg;
        seg.s[0] = 0u; seg.s[8] = (unsigned)LEVELS * tpl;
        for (int k = 1; k < 8; ++k) {
            const double target = tot * (double)k / 8.0;
            int l = 0;
            while (l < LEVELS - 1 && cum[l+1] <= target) ++l;
            const double frac = (target - cum[l]) / wl[l];
            unsigned tk = (unsigned)l * tpl + (unsigned)(frac * (double)tpl);
            if (tk > seg.s[8]) tk = seg.s[8];
            if (tk < seg.s[k-1]) tk = seg.s[k-1];
            seg.s[k] = tk;
        }

        ngp_gather_xcd<<<dim3(2048), dim3(256), 0, stream>>>(
            x, table, out_t, res, seg, n_points);
        ngp_transpose_lds<<<dim3(n_points / 256u), dim3(256), 0, stream>>>(
            out_t, (f32x4*)d_out, n_points);
    } else {
        const unsigned total = n_points * LEVELS;
        const unsigned nblk = (total + 255u) / 256u;
        ngp_encode_direct<<<dim3(nblk), dim3(256), 0, stream>>>(
            x, table, (f32x2*)d_out, res, n_points);
    }
}

// Round 11
// 614.905 us; speedup vs baseline: 1.6845x; 1.4006x over previous
//
#include <hip/hip_runtime.h>
#include <math.h>

// Instant-NGP hash grid encoder, MI355X. Round 11.
//
// Established evidence: launch boundaries are the ONLY working phasing
// (r6 best 638 us; r9 queue/r10 XCD-partition drift -> 0.8-1.0 GB FETCH).
// r10 also exposed by subtraction that temporal final stores cost the
// transpose 2.2x (86 -> 195 us): wave-contiguous full-line write streams
// want nt (write-around), temporal thrashes L2 against gather-warm lines.
// This round:
//  1. Levels 0-5 fused in ONE dispatch: combined table footprint 2.2 MB
//     < 4 MB XCD L2 -> no phasing needed; saves 5 launch gaps + 5x x-read.
//  2. Levels 6-15: r6's proven per-level dispatches, unchanged.
//  3. Transpose: nt stores REVERTED (r10 lesson), nt loads (read-once
//     stream), single-sync structure (16 loads in flight, 1 barrier, 8
//     coalesced 1 KB/wave nt stores). 34 KB LDS -> 4 blk/CU; r6 proved
//     this kernel is insensitive to occupancy (37% == 66%).

#define LEVELS 16
#define LOG2_T 19
#define TMASK ((1u << LOG2_T) - 1u)
#define N_COARSE 6           // levels 0..5 table sum ~2.2 MB: L2-safe fused

typedef float f32x2 __attribute__((ext_vector_type(2)));
typedef float f32x4 __attribute__((ext_vector_type(4)));

struct ResArgs { float r[LEVELS]; };

// Proven 8-load encode (bit-identical results r3/r6, absmax 1.9e-6).
__device__ __forceinline__ f32x2 encode_one(
    const f32x2* __restrict__ tbl, float rf,
    float x0, float x1, float x2)
{
    const float sx = x0 * rf, sy = x1 * rf, sz = x2 * rf;
    const float px = floorf(sx), py = floorf(sy), pz = floorf(sz);
    const float fx = sx - px, fy = sy - py, fz = sz - pz;
    const unsigned ix = (unsigned)px, iy = (unsigned)py, iz = (unsigned)pz;
    const unsigned hx0 = ix, hx1 = ix + 1u;
    const unsigned hy0 = iy * 2654435761u, hy1 = hy0 + 2654435761u;
    const unsigned hz0 = iz * 805459861u,  hz1 = hz0 + 805459861u;
    const f32x2 c000 = tbl[(hx0 ^ hy0 ^ hz0) & TMASK];
    const f32x2 c100 = tbl[(hx1 ^ hy0 ^ hz0) & TMASK];
    const f32x2 c010 = tbl[(hx0 ^ hy1 ^ hz0) & TMASK];
    const f32x2 c110 = tbl[(hx1 ^ hy1 ^ hz0) & TMASK];
    const f32x2 c001 = tbl[(hx0 ^ hy0 ^ hz1) & TMASK];
    const f32x2 c101 = tbl[(hx1 ^ hy0 ^ hz1) & TMASK];
    const f32x2 c011 = tbl[(hx0 ^ hy1 ^ hz1) & TMASK];
    const f32x2 c111 = tbl[(hx1 ^ hy1 ^ hz1) & TMASK];
    const float wx1 = fx, wx0 = 1.0f - fx;
    const float wy1 = fy, wy0 = 1.0f - fy;
    const float wz1 = fz, wz0 = 1.0f - fz;
    const float w00 = wy0 * wz0, w10 = wy1 * wz0;
    const float w01 = wy0 * wz1, w11 = wy1 * wz1;
    float w, a0, a1;
    w = wx0 * w00; a0 = w * c000.x;          a1 = w * c000.y;
    w = wx1 * w00; a0 = fmaf(w, c100.x, a0); a1 = fmaf(w, c100.y, a1);
    w = wx0 * w10; a0 = fmaf(w, c010.x, a0); a1 = fmaf(w, c010.y, a1);
    w = wx1 * w10; a0 = fmaf(w, c110.x, a0); a1 = fmaf(w, c110.y, a1);
    w = wx0 * w01; a0 = fmaf(w, c001.x, a0); a1 = fmaf(w, c001.y, a1);
    w = wx1 * w01; a0 = fmaf(w, c101.x, a0); a1 = fmaf(w, c101.y, a1);
    w = wx0 * w11; a0 = fmaf(w, c011.x, a0); a1 = fmaf(w, c011.y, a1);
    w = wx1 * w11; a0 = fmaf(w, c111.x, a0); a1 = fmaf(w, c111.y, a1);
    f32x2 o; o.x = a0; o.y = a1;
    return o;
}

// ---- Fused coarse levels 0..5: one dispatch, tiny L2-resident tables ----
__global__ __launch_bounds__(256) void ngp_gather_coarse(
    const float* __restrict__ x,
    const float* __restrict__ table,
    f32x2* __restrict__ out_t,     // [LEVELS][n] scratch
    ResArgs res, unsigned n)
{
    const unsigned p = blockIdx.x * 256u + threadIdx.x;
    if (p >= n) return;
    const float x0 = __builtin_nontemporal_load(&x[3u*p]);
    const float x1 = __builtin_nontemporal_load(&x[3u*p+1u]);
    const float x2 = __builtin_nontemporal_load(&x[3u*p+2u]);

    #pragma unroll 1   // sequential levels: keeps VGPR low, tables L1-hot
    for (int l = 0; l < N_COARSE; ++l) {
        const f32x2* __restrict__ tbl =
            (const f32x2*)table + ((size_t)l << LOG2_T);
        f32x2 o = encode_one(tbl, res.r[l], x0, x1, x2);
        __builtin_nontemporal_store(o, &out_t[(size_t)l * n + p]);
    }
}

// ---- Per-level fine gather (r6-proven, unchanged) -----------------------
__global__ __launch_bounds__(256) void ngp_gather_level(
    const float* __restrict__ x,
    const float* __restrict__ table,
    f32x2* __restrict__ out_t,
    float rf, int level, unsigned n)
{
    const unsigned p = blockIdx.x * 256u + threadIdx.x;
    if (p >= n) return;
    const float x0 = __builtin_nontemporal_load(&x[3u*p]);
    const float x1 = __builtin_nontemporal_load(&x[3u*p+1u]);
    const float x2 = __builtin_nontemporal_load(&x[3u*p+2u]);
    const f32x2* __restrict__ tbl =
        (const f32x2*)table + ((size_t)level << LOG2_T);
    f32x2 o = encode_one(tbl, rf, x0, x1, x2);
    __builtin_nontemporal_store(o, &out_t[(size_t)level * n + p]);
}

// ---- Transpose [L][N] -> [N][L]: single-sync, nt both sides -------------
// 256-pt tile, 16 b64 nt loads/thread all in flight, ONE barrier, then
// 8 f32x4 nt stores/thread (1 KB/wave contiguous per instruction).
__global__ __launch_bounds__(256) void ngp_transpose_lds(
    const f32x2* __restrict__ out_t,
    f32x4* __restrict__ out,       // [n*8] f32x4
    unsigned n)                    // host guarantees n % 256 == 0
{
    __shared__ f32x2 lds[256][LEVELS + 1];   // 34816 B -> 4 blocks/CU
    const unsigned t = threadIdx.x;
    const unsigned p0 = blockIdx.x * 256u;

    #pragma unroll
    for (int j = 0; j < LEVELS; ++j) {
        const unsigned idx = (unsigned)j * 256u + t;   // 0..4095
        const unsigned l  = idx >> 8;                  // wave-uniform row
        const unsigned pp = idx & 255u;
        lds[pp][l] =
            __builtin_nontemporal_load(&out_t[(size_t)l * n + p0 + pp]);
    }
    __syncthreads();
    #pragma unroll
    for (int j = 0; j < 8; ++j) {
        const unsigned g = (unsigned)j * 256u + t;     // 0..2047
        const unsigned p = g >> 3, q = g & 7u;
        const f32x2 a = lds[p][2u*q];
        const f32x2 b = lds[p][2u*q + 1u];
        f32x4 v; v.x = a.x; v.y = a.y; v.z = b.x; v.w = b.y;
        __builtin_nontemporal_store(v, &out[(size_t)p0 * 8u + g]);
    }
}

// ---- Fallback (round-3 proven): direct point-major ----------------------
__global__ __launch_bounds__(256) void ngp_encode_direct(
    const float* __restrict__ x,
    const float* __restrict__ table,
    f32x2* __restrict__ out,
    ResArgs res,
    unsigned n_points)
{
    const unsigned t = blockIdx.x * 256u + threadIdx.x;
    const unsigned level = t & (LEVELS - 1u);
    const unsigned p = t >> 4;
    if (p >= n_points) return;
    const float x0 = x[3u*p], x1 = x[3u*p+1u], x2 = x[3u*p+2u];
    const f32x2* __restrict__ tbl =
        (const f32x2*)table + ((size_t)level << LOG2_T);
    f32x2 o = encode_one(tbl, res.r[level], x0, x1, x2);
    __builtin_nontemporal_store(o, &out[t]);
}

extern "C" void kernel_launch(void* const* d_in, const int* in_sizes, int n_in,
                              void* d_out, int out_size, void* d_ws, size_t ws_size,
                              hipStream_t stream) {
    const float* x     = (const float*)d_in[0];
    const float* table = (const float*)d_in[1];
    const unsigned n_points = (unsigned)(in_sizes[0] / 3);

    // numpy RES replication (same host libm).
    ResArgs res;
    const double scale = exp((log(512.0) - log(16.0)) / 15.0);
    for (int l = 0; l < LEVELS; ++l) {
        res.r[l] = (float)floor(16.0 * pow(scale, (double)l));
    }

    const size_t scratch_needed = (size_t)LEVELS * n_points * sizeof(f32x2);
    const bool fits = (ws_size >= scratch_needed) && (n_points % 256u == 0u);

    if (fits) {
        f32x2* out_t = (f32x2*)d_ws;
        const unsigned nblk = n_points / 256u;
        ngp_gather_coarse<<<dim3(nblk), dim3(256), 0, stream>>>(
            x, table, out_t, res, n_points);
        for (int l = N_COARSE; l < LEVELS; ++l) {
            ngp_gather_level<<<dim3(nblk), dim3(256), 0, stream>>>(
                x, table, out_t, res.r[l], l, n_points);
        }
        ngp_transpose_lds<<<dim3(nblk), dim3(256), 0, stream>>>(
            out_t, (f32x4*)d_out, n_points);
    } else {
        const unsigned total = n_points * LEVELS;
        const unsigned nblk = (total + 255u) / 256u;
        ngp_encode_direct<<<dim3(nblk), dim3(256), 0, stream>>>(
            x, table, (f32x2*)d_out, res, n_points);
    }
}